// Round 11
// baseline (89.155 us; speedup 1.0000x reference)
//
#include <hip/hip_runtime.h>
#include <stdint.h>

#define SEQL 4096
#define NHEAD 8
#define DHEAD 64
#define HEADELEMS (SEQL * DHEAD)  // 262144
#define KVBLK 64

typedef unsigned short u16;
typedef __bf16 bf16x8 __attribute__((ext_vector_type(8)));
typedef float f32x16 __attribute__((ext_vector_type(16)));

extern "C" __device__ float __ocml_native_exp2_f32(float);  // raw v_exp_f32

__device__ __forceinline__ u16 f2bf(float f) {
  union { float f; uint32_t u; } x; x.f = f;
  uint32_t r = x.u + 0x7fffu + ((x.u >> 16) & 1u);
  return (u16)(r >> 16);
}

__device__ __forceinline__ uint32_t cvt_pk_bf16(float lo, float hi) {
  uint32_t r;
  asm("v_cvt_pk_bf16_f32 %0, %1, %2" : "=v"(r) : "v"(lo), "v"(hi));
  return r;
}

// v_permlane32_swap_b32 vdst, vsrc (verified r4):
//   new_vdst[32:63] = old_vsrc[0:31]; new_vsrc[0:31] = old_vdst[32:63].
__device__ __forceinline__ void pl32_swap(uint32_t& dst, uint32_t& src) {
  asm("v_permlane32_swap_b32 %0, %1" : "+v"(dst), "+v"(src));
}

// pack 8 f32 P-values into a PV A-fragment (r4-verified pairing)
__device__ __forceinline__ bf16x8 pack_paf(const float* e8) {
  uint32_t w0 = cvt_pk_bf16(e8[0], e8[1]);
  uint32_t w1 = cvt_pk_bf16(e8[2], e8[3]);
  uint32_t w2 = cvt_pk_bf16(e8[4], e8[5]);
  uint32_t w3 = cvt_pk_bf16(e8[6], e8[7]);
  pl32_swap(w0, w2);
  pl32_swap(w1, w3);
  union { uint32_t u[4]; bf16x8 v; } pw;
  pw.u[0] = w0; pw.u[1] = w1; pw.u[2] = w2; pw.u[3] = w3;
  return pw.v;
}

#define GLDS16(g, l)                                                            \
  __builtin_amdgcn_global_load_lds(                                             \
      (const __attribute__((address_space(1))) uint32_t*)(g),                   \
      (__attribute__((address_space(3))) uint32_t*)(l), 16, 0, 0)

// ---------------- Projection (validated r1..r9) -----------------------------
__global__ __launch_bounds__(256) void proj_kernel(
    const float* __restrict__ q, const float* __restrict__ k, const float* __restrict__ v,
    const float* __restrict__ qw, const float* __restrict__ qb,
    const float* __restrict__ kw, const float* __restrict__ kb,
    const float* __restrict__ vw, const float* __restrict__ vb,
    u16* __restrict__ Qp, u16* __restrict__ Kp, u16* __restrict__ vhT) {
  const float* X; const float* W; const float* B; float scale;
  if (blockIdx.y == 0)      { X = q; W = qw; B = qb; scale = 0.125f * 1.44269504089f; }
  else if (blockIdx.y == 1) { X = k; W = kw; B = kb; scale = 1.0f; }
  else                      { X = v; W = vw; B = vb; scale = 1.0f; }

  __shared__ float xs[16][64];
  __shared__ __align__(16) u16 vtile[64][136];
  const int t = threadIdx.x;
  const int rowbase = blockIdx.x * 16;
  for (int i = t; i < 16 * 64; i += 256) xs[i >> 6][i & 63] = X[rowbase * 64 + i];
  __syncthreads();

  const int c0 = t * 2;
  float acc0[16] = {}, acc1[16] = {};
  for (int kk = 0; kk < 64; ++kk) {
    const float2 w = *(const float2*)(W + kk * 512 + c0);
    #pragma unroll
    for (int r = 0; r < 16; ++r) {
      const float x = xs[r][kk];
      acc0[r] = fmaf(x, w.x, acc0[r]);
      acc1[r] = fmaf(x, w.y, acc1[r]);
    }
  }
  const float b0 = B[c0], b1 = B[c0 + 1];

  if (blockIdx.y != 2) {
    u16* __restrict__ P = (blockIdx.y == 0) ? Qp : Kp;
    #pragma unroll
    for (int r = 0; r < 16; ++r) {
      const u16 o0 = f2bf((acc0[r] + b0) * scale);
      const u16 o1 = f2bf((acc1[r] + b1) * scale);
      *(uint32_t*)(P + (rowbase + r) * 512 + c0) = ((uint32_t)o1 << 16) | (uint32_t)o0;
    }
  } else {
    const int dd = c0 & 63, cg = c0 >> 6;
    #pragma unroll
    for (int r = 0; r < 16; ++r) {
      vtile[dd][r * 8 + cg]     = f2bf(acc0[r] + b0);
      vtile[dd + 1][r * 8 + cg] = f2bf(acc1[r] + b1);
    }
    __syncthreads();
    const int h = rowbase >> 9;
    const int ibase = (rowbase & 511) * 8;
    u16* __restrict__ dst = vhT + h * HEADELEMS;
    #pragma unroll
    for (int rep = 0; rep < 4; ++rep) {
      const int n = t + rep * 256;
      const int d2 = n >> 4, m = n & 15;
      *(uint4*)(dst + d2 * 4096 + ibase + m * 8) = *(const uint4*)(&vtile[d2][m * 8]);
    }
  }
}

// ---------------- Flash attention: 64 q/wave, 1 LDS read -> 4 MFMA ----------
// SPLIT-way key split; grid = 16*SPLIT*8 (h = bid&7, head-per-XCD).
// Block: 4 waves x 64 q = 256 q. Ring of 3 x 16KB slots (K[64][64]@+0,
// V^T[64][64]@+8192) + Q[256][64] @+48KB = 80 KiB. Counted vmcnt (prefetch
// depth 2: steady vmcnt(4), drain 0). Each K/V fragment read once feeds
// qfA and qfB MFMAs (halves LDS read traffic vs r9).
// 32x32x16 layouts: A lane l: row=l&31, k=(l>>5)*8+j. B: col=l&31, same k.
//                   C/D lane l: col=l&31, row=(reg&3)+8*(reg>>2)+4*(l>>5).
template <int SPLIT>
__global__ __launch_bounds__(256, 2) void attn_kernel(
    const u16* __restrict__ Qp, const u16* __restrict__ Kp,
    const u16* __restrict__ vhT, float* __restrict__ cxp, float* __restrict__ lsp) {
  constexpr int TPQ = 64 / SPLIT;  // 64-key tiles per split section
  const int h = blockIdx.x & 7, idx = blockIdx.x >> 3;
  const int qb = idx / SPLIT, part = idx % SPLIT;
  const int t = threadIdx.x, lane = t & 63;
  const int l32 = lane & 31, hi = lane >> 5;

  __shared__ __align__(16) char smem[3 * 16384 + 32768];  // 80 KiB
  char* const qlds = smem + 49152;

  const u16* __restrict__ Qh = Qp + h * HEADELEMS;
  const u16* __restrict__ Kh = Kp + h * HEADELEMS;
  const u16* __restrict__ VTh = vhT + h * HEADELEMS;

  int koff[2], voff[2];
  #pragma unroll
  for (int i = 0; i < 2; ++i) {
    const int n = t + i * 256;
    const int r = n >> 3, c = (n & 7) ^ (r & 7);
    koff[i] = r * 64 + c * 8;    // K rows, XOR-swizzled source
    voff[i] = r * 4096 + c * 8;  // V^T rows (stride 4096)
  }
  const int wuni = (t & 192) * 16;  // wave-uniform LDS chunk base (bytes)

#define STAGE(j, slot)                                                         \
  {                                                                            \
    const int kb_ = (part * TPQ + (j)) * KVBLK;                                \
    GLDS16(Kh + kb_ * 64 + koff[0], (slot));                                   \
    GLDS16(Kh + kb_ * 64 + koff[1], (slot) + 4096);                            \
    GLDS16(VTh + kb_ + voff[0], (slot) + 8192);                                \
    GLDS16(VTh + kb_ + voff[1], (slot) + 12288);                               \
  }

  // prologue: Q (8 DMA), tiles 0,1 (8 DMA) -- emission order FENCED.
  {
    const u16* __restrict__ qsrc = Qh + qb * 256 * 64;  // [256 q][64 d] linear
    #pragma unroll
    for (int i = 0; i < 8; ++i) {
      const int n = t + i * 256;
      GLDS16(qsrc + (n >> 3) * 64 + (n & 7) * 8, qlds + i * 4096 + wuni);
    }
  }
  __builtin_amdgcn_sched_barrier(0);
  STAGE(0, smem + wuni);
  __builtin_amdgcn_sched_barrier(0);
  STAGE(1, smem + 16384 + wuni);
  __builtin_amdgcn_sched_barrier(0);

  // retire Q batch (oldest 8 of 16), sync, read Q fragments (one-off).
  asm volatile("s_waitcnt vmcnt(8)" ::: "memory");
  __builtin_amdgcn_s_barrier();
  __builtin_amdgcn_sched_barrier(0);

  const int qrlA = (t >> 6) * 64 + l32;
  bf16x8 qfA[4], qfB[4];
  #pragma unroll
  for (int ks = 0; ks < 4; ++ks) {
    qfA[ks] = *(const bf16x8*)(qlds + qrlA * 128 + ks * 32 + hi * 16);
    qfB[ks] = *(const bf16x8*)(qlds + (qrlA + 32) * 128 + ks * 32 + hi * 16);
  }

  const f32x16 z16 = {0,0,0,0,0,0,0,0,0,0,0,0,0,0,0,0};
  f32x16 caA0 = z16, caA1 = z16, caB0 = z16, caB1 = z16;
  float lsA[4] = {0.f, 0.f, 0.f, 0.f}, lsB[4] = {0.f, 0.f, 0.f, 0.f};

  for (int it = 0; it < TPQ; ++it) {
    // batch `it` landed: keep only the one newer batch in flight
    if (it < TPQ - 1) asm volatile("s_waitcnt vmcnt(4) lgkmcnt(0)" ::: "memory");
    else              asm volatile("s_waitcnt vmcnt(0) lgkmcnt(0)" ::: "memory");
    __builtin_amdgcn_s_barrier();
    __builtin_amdgcn_sched_barrier(0);

    char* const cb = smem + (it % 3) * 16384;
    if (it + 2 < TPQ) STAGE(it + 2, smem + ((it + 2) % 3) * 16384 + wuni);
    __builtin_amdgcn_sched_barrier(0);

    // QK^T: each K fragment feeds 4 MFMAs (A/B q-groups x key-halves)
    f32x16 sA0 = z16, sA1 = z16, sB0 = z16, sB1 = z16;
    const int ar0 = l32, ar1 = l32 + 32;
    __builtin_amdgcn_s_setprio(1);
    #pragma unroll
    for (int ks = 0; ks < 4; ++ks) {
      const int c = ks * 2 + hi;
      const bf16x8 k0 = *(const bf16x8*)(cb + ar0 * 128 + ((c ^ (ar0 & 7)) * 16));
      const bf16x8 k1 = *(const bf16x8*)(cb + ar1 * 128 + ((c ^ (ar1 & 7)) * 16));
      sA0 = __builtin_amdgcn_mfma_f32_32x32x16_bf16(k0, qfA[ks], sA0, 0, 0, 0);
      sA1 = __builtin_amdgcn_mfma_f32_32x32x16_bf16(k1, qfA[ks], sA1, 0, 0, 0);
      sB0 = __builtin_amdgcn_mfma_f32_32x32x16_bf16(k0, qfB[ks], sB0, 0, 0, 0);
      sB1 = __builtin_amdgcn_mfma_f32_32x32x16_bf16(k1, qfB[ks], sB1, 0, 0, 0);
    }
    __builtin_amdgcn_s_setprio(0);

    // softmax + pack, group A then B (eX dies into pafX, keeps VGPR peak down)
    bf16x8 pafA[4], pafB[4];
    {
      float e[32];
      #pragma unroll
      for (int r = 0; r < 16; ++r) { e[r] = __ocml_native_exp2_f32(sA0[r]); lsA[r & 3] += e[r]; }
      #pragma unroll
      for (int r = 0; r < 16; ++r) { e[16 + r] = __ocml_native_exp2_f32(sA1[r]); lsA[r & 3] += e[16 + r]; }
      #pragma unroll
      for (int ksl = 0; ksl < 4; ++ksl) pafA[ksl] = pack_paf(e + ksl * 8);
    }
    {
      float e[32];
      #pragma unroll
      for (int r = 0; r < 16; ++r) { e[r] = __ocml_native_exp2_f32(sB0[r]); lsB[r & 3] += e[r]; }
      #pragma unroll
      for (int r = 0; r < 16; ++r) { e[16 + r] = __ocml_native_exp2_f32(sB1[r]); lsB[r & 3] += e[16 + r]; }
      #pragma unroll
      for (int ksl = 0; ksl < 4; ++ksl) pafB[ksl] = pack_paf(e + ksl * 8);
    }

    // PV: each V fragment feeds 4 MFMAs
    #pragma unroll
    for (int ksl = 0; ksl < 4; ++ksl) {
      const int cl = ksl * 2 + hi;
      const int vr0 = l32, vr1 = l32 + 32;
      const bf16x8 v0 = *(const bf16x8*)(cb + 8192 + vr0 * 128 + ((cl ^ (vr0 & 7)) * 16));
      const bf16x8 v1 = *(const bf16x8*)(cb + 8192 + vr1 * 128 + ((cl ^ (vr1 & 7)) * 16));
      __builtin_amdgcn_s_setprio(1);
      caA0 = __builtin_amdgcn_mfma_f32_32x32x16_bf16(pafA[ksl], v0, caA0, 0, 0, 0);
      caA1 = __builtin_amdgcn_mfma_f32_32x32x16_bf16(pafA[ksl], v1, caA1, 0, 0, 0);
      caB0 = __builtin_amdgcn_mfma_f32_32x32x16_bf16(pafB[ksl], v0, caB0, 0, 0, 0);
      caB1 = __builtin_amdgcn_mfma_f32_32x32x16_bf16(pafB[ksl], v1, caB1, 0, 0, 0);
      __builtin_amdgcn_s_setprio(0);
    }
  }
#undef STAGE

  // epilogue: UNNORMALIZED partial ctx + lsum for this key section
  float lsumA = (lsA[0] + lsA[1]) + (lsA[2] + lsA[3]);
  float lsumB = (lsB[0] + lsB[1]) + (lsB[2] + lsB[3]);
  lsumA += __shfl_xor(lsumA, 32);
  lsumB += __shfl_xor(lsumB, 32);
  const int q0 = qb * 256 + (t >> 6) * 64;
  float* __restrict__ ch = cxp + (part * NHEAD + h) * HEADELEMS;
  #pragma unroll
  for (int reg = 0; reg < 16; ++reg) {
    const int crw = (reg & 3) + 8 * (reg >> 2) + 4 * hi;
    ch[(q0 + crw) * 64 + l32]           = caA0[reg];
    ch[(q0 + crw) * 64 + 32 + l32]      = caA1[reg];
    ch[(q0 + 32 + crw) * 64 + l32]      = caB0[reg];
    ch[(q0 + 32 + crw) * 64 + 32 + l32] = caB1[reg];
  }
  if (hi == 0) {
    lsp[(part * NHEAD + h) * SEQL + q0 + l32]      = lsumA;
    lsp[(part * NHEAD + h) * SEQL + q0 + 32 + l32] = lsumB;
  }
}

// ---------------- Fused combine + output projection (LDS-staged, r9-valid) -
template <int SPLIT>
__global__ __launch_bounds__(256) void outproj_kernel(
    const float* __restrict__ cxp, const float* __restrict__ lsp,
    const float* __restrict__ W, const float* __restrict__ B,
    float* __restrict__ out) {
  const int t = threadIdx.x;
  const int r0 = blockIdx.x * 8;       // 8 out-rows, one head (8 | 512)
  const int hh = r0 >> 9;
  const int sb0 = (r0 & 511) * 8;      // first of 64 ctx rows

  __shared__ float cn[64][64];         // 16 KB
  __shared__ float invs[64];

  if (t < 64) {
    float s = 0.f;
    #pragma unroll
    for (int p = 0; p < SPLIT; ++p) s += lsp[(p * NHEAD + hh) * SEQL + sb0 + t];
    invs[t] = 1.0f / s;
  }
  __syncthreads();

  #pragma unroll
  for (int i = 0; i < 4; ++i) {
    const int n = (t + i * 256) * 4;   // element offset, coalesced float4
    const int s = n >> 6;
    const int base = hh * HEADELEMS + sb0 * 64 + n;
    float4 av = *(const float4*)(cxp + base);
    #pragma unroll
    for (int p = 1; p < SPLIT; ++p) {
      const float4 bv = *(const float4*)(cxp + p * NHEAD * HEADELEMS + base);
      av.x += bv.x; av.y += bv.y; av.z += bv.z; av.w += bv.w;
    }
    const float inv = invs[s];
    av.x *= inv; av.y *= inv; av.z *= inv; av.w *= inv;
    *(float4*)(&cn[s][n & 63]) = av;
  }
  __syncthreads();

  const int col = t & 63;
  const int lr = (t >> 6) * 2;         // this wave's two local out-rows
  float acc0 = 0.f, acc1 = 0.f;
  #pragma unroll 8
  for (int kk = 0; kk < 512; ++kk) {
    const float wv = W[kk * 64 + col];
    acc0 = fmaf(cn[lr * 8 + (kk >> 6)][kk & 63], wv, acc0);
    acc1 = fmaf(cn[lr * 8 + 8 + (kk >> 6)][kk & 63], wv, acc1);
  }
  const float b = B[col];
  out[(r0 + lr) * 64 + col] = acc0 + b;
  out[(r0 + lr + 1) * 64 + col] = acc1 + b;
}

extern "C" void kernel_launch(void* const* d_in, const int* in_sizes, int n_in,
                              void* d_out, int out_size, void* d_ws, size_t ws_size,
                              hipStream_t stream) {
  const float* q  = (const float*)d_in[0];
  const float* k  = (const float*)d_in[1];
  const float* v  = (const float*)d_in[2];
  const float* qw = (const float*)d_in[3];
  const float* qb = (const float*)d_in[4];
  const float* kw = (const float*)d_in[5];
  const float* kb = (const float*)d_in[6];
  const float* vw = (const float*)d_in[7];
  const float* vb = (const float*)d_in[8];
  const float* ow = (const float*)d_in[9];
  const float* ob = (const float*)d_in[10];

  char* ws = (char*)d_ws;
  u16* Qp    = (u16*)(ws);                  // 4 MB bf16 [4096,512], pre-scaled
  u16* Kp    = (u16*)(ws + (4u << 20));     // 4 MB
  u16* vhT   = (u16*)(ws + (8u << 20));     // 4 MB bf16 [8][64][4096]
  float* cxp = (float*)(ws + (12u << 20));  // SPLIT x 8 MB f32 partials
  float* out = (float*)d_out;

  proj_kernel<<<dim3(SEQL / 16, 3), 256, 0, stream>>>(q, k, v, qw, qb, kw, kb, vw, vb,
                                                      Qp, Kp, vhT);

  const size_t need4 = (12u << 20) + 4u * ((8u << 20) + NHEAD * SEQL * 4u);
  if (ws_size >= need4) {
    float* lsp = (float*)(ws + (12u << 20) + 4u * (8u << 20));
    attn_kernel<4><<<16 * 4 * 8, 256, 0, stream>>>(Qp, Kp, vhT, cxp, lsp);
    outproj_kernel<4><<<SEQL / 8, 256, 0, stream>>>(cxp, lsp, ow, ob, out);
  } else {
    float* lsp = (float*)(ws + (12u << 20) + 2u * (8u << 20));
    attn_kernel<2><<<16 * 2 * 8, 256, 0, stream>>>(Qp, Kp, vhT, cxp, lsp);
    outproj_kernel<2><<<SEQL / 8, 256, 0, stream>>>(cxp, lsp, ow, ob, out);
  }
}